// Round 8
// baseline (117.947 us; speedup 1.0000x reference)
//
#include <hip/hip_runtime.h>
#include <math.h>

// LossLayer: dist[b,r] = ||W[b]-R[r]||2 ; pred = one_hot(argmax_r dist) ;
// loss = mean(1 + dist[b,y] - dist[b, top2-excluding-y-at-top1]), y=argmax(label[b])
//
// R8: seven rounds of LDS+barrier structures all pinned at 46-60 us, every
// pipe <22%. Root causes identified: (1) every __syncthreads drains vmcnt(0);
// (2) s_load (scalar W) and ds_read SHARE lgkmcnt, and SMEM is out-of-order,
// so each scalar-use forces lgkmcnt(0) == full ds_read pipeline collapse
// (R7: VALUBusy 12%, VGPR 184); (3) block geometry caps waves/CU.
// Fix: NO LDS, NO barriers in the hot loop.
//   - tiny kernel transposes re -> reT[d4][r] (float4 of dims 4d4..4d4+3,
//     128 KB, in d_ws): lane r reads reT[d4*64+r] = coalesced 1 KB/wave
//     vector loads (vmcnt), L2-hot.
//   - W rows via readfirstlane-forced SCALAR loads (lgkmcnt) -- with zero
//     ds_reads, lgkm waits only ever touch SMEM. Independent counters.
//   - JB=4 rows/wave: 4 independent FMA chains (ILP), reT traffic
//     4x128 KB/CU = 512 KB (~3.3 us L1) ~= VALU 3.4 us -- balanced.
#define NB 4096
#define NR 64
#define JB 4            // b-rows per wave
#define WVS 4           // waves per block
#define BBB (JB * WVS)  // 16 b-rows per block; grid = 256

__global__ __launch_bounds__(256) void transpose_re_kernel(
    const float* __restrict__ re, float4* __restrict__ reT)
{
    // reT[d4*64 + r] = float4 of re[r][4*d4 .. 4*d4+3]
    int t  = blockIdx.x * 256 + threadIdx.x;    // 8192 threads: grid 32
    int r  = t >> 7;                            // relation row
    int d4 = t & 127;                           // f4 column
    // read coalesced (lane-consecutive d4); scattered writes don't stall
    reT[d4 * 64 + r] = ((const float4*)re)[r * 128 + d4];
}

__global__ __launch_bounds__(256) void fused_loss_kernel(
    const float* __restrict__ w,
    const float4* __restrict__ reT,
    const float* __restrict__ label,
    float* __restrict__ out,
    float* __restrict__ ws)
{
    __shared__ float terms[WVS];

    const int tid = threadIdx.x;
    const int wv  = tid >> 6;       // wave id
    const int r   = tid & 63;       // lane = relation 0..63
    const int b0  = blockIdx.x * BBB;

    // W row base pointers, readfirstlane-forced scalar (R6: VGPR 32 pattern)
    const float4* wr[JB];
    #pragma unroll
    for (int j = 0; j < JB; j++) {
        int bu = __builtin_amdgcn_readfirstlane(b0 + wv * JB + j);
        wr[j] = (const float4*)(w + (size_t)bu * 512);
    }

    float4 acc[JB];
    #pragma unroll
    for (int j = 0; j < JB; j++) acc[j] = (float4){0.f, 0.f, 0.f, 0.f};

    // hot loop: 128 coalesced vector loads (vmcnt) + scalar W stream (lgkm);
    // no LDS, no barriers -- both streams pipeline independently.
    #pragma unroll 8
    for (int d4 = 0; d4 < 128; d4++) {
        float4 rv = reT[d4 * 64 + r];
        #pragma unroll
        for (int j = 0; j < JB; j++) {
            float4 a = wr[j][d4];               // scalar load, sK$/L2
            float dx;
            dx = a.x - rv.x; acc[j].x = fmaf(dx, dx, acc[j].x);
            dx = a.y - rv.y; acc[j].y = fmaf(dx, dx, acc[j].y);
            dx = a.z - rv.z; acc[j].z = fmaf(dx, dx, acc[j].z);
            dx = a.w - rv.w; acc[j].w = fmaf(dx, dx, acc[j].w);
        }
    }

    // ---- epilogue per j: top-2/argmax + label argmax + loss term ----
    float lsum = 0.0f;
    #pragma unroll
    for (int j = 0; j < JB; j++) {
        int b = b0 + wv * JB + j;
        float d = sqrtf((acc[j].x + acc[j].y) + (acc[j].z + acc[j].w));

        float m1 = d; int i1 = r; float m2 = -3.0e38f;
        #pragma unroll
        for (int mask = 1; mask <= 32; mask <<= 1) {
            float om1 = __shfl_xor(m1, mask, 64);
            int   oi1 = __shfl_xor(i1, mask, 64);
            float om2 = __shfl_xor(m2, mask, 64);
            bool ob1 = (om1 > m1) || (om1 == m1 && oi1 < i1);
            float w1 = ob1 ? om1 : m1;  int wi1 = ob1 ? oi1 : i1;
            float l1 = ob1 ? m1 : om1;          // loser's top-1 (value only)
            float c2 = ob1 ? om2 : m2;          // winner's top-2 (value only)
            m1 = w1; i1 = wi1;
            m2 = (c2 > l1) ? c2 : l1;
        }

        float lv = label[(size_t)b * 64 + r]; int ly = r;
        #pragma unroll
        for (int mask = 1; mask <= 32; mask <<= 1) {
            float ov = __shfl_xor(lv, mask, 64);
            int   oy = __shfl_xor(ly, mask, 64);
            if (ov > lv || (ov == lv && oy < ly)) { lv = ov; ly = oy; }
        }
        int y = ly;

        float plus  = __shfl(d, y, 64);       // dist[b][y]
        float minus = (i1 == y) ? m2 : m1;    // top-2 value if top-1 == y
        lsum += 1.0f + plus - minus;

        out[(size_t)b * 64 + r] = (i1 == r) ? 1.0f : 0.0f;   // pred one-hot
    }

    if (r == 0) terms[wv] = lsum;

    // ---- fused loss reduction: block partial -> device atomic -> last block
    __syncthreads();
    if (tid == 0) {
        float t = ((terms[0] + terms[1]) + (terms[2] + terms[3])) * (1.0f / NB);
        atomicAdd(ws, t);                     // ws[0] = loss accumulator (zeroed)
        __threadfence();                      // order add before counter inc
        unsigned old = atomicAdd((unsigned*)(ws + 1), 1u);   // ws[1] = counter
        if (old == (unsigned)(gridDim.x - 1)) {
            float total = atomicAdd(ws, 0.0f);   // all 256 adds visible
            out[(size_t)NB * NR] = total;
        }
    }
}

extern "C" void kernel_launch(void* const* d_in, const int* in_sizes, int n_in,
                              void* d_out, int out_size, void* d_ws, size_t ws_size,
                              hipStream_t stream) {
    const float* w   = (const float*)d_in[0];   // [4096,512]
    const float* re  = (const float*)d_in[1];   // [64,512]
    const float* lab = (const float*)d_in[2];   // [4096,64]
    float* out = (float*)d_out;                 // pred [4096,64] ++ loss [1]
    float* ws  = (float*)d_ws;                  // [0]=loss acc, [1]=done counter
    float4* reT = (float4*)((char*)d_ws + 1024);// [128][64] f4 = 128 KB scratch

    hipMemsetAsync(ws, 0, 8, stream);           // zero acc + counter (graph-safe)
    transpose_re_kernel<<<32, 256, 0, stream>>>(re, reT);
    fused_loss_kernel<<<NB / BBB, 256, 0, stream>>>(w, reT, lab, out, ws);
}

// Round 9
// 96.222 us; speedup vs baseline: 1.2258x; 1.2258x over previous
//
#include <hip/hip_runtime.h>
#include <math.h>

// LossLayer: dist[b,r] = ||W[b]-R[r]||2 ; pred = one_hot(argmax_r dist) ;
// loss = mean(1 + dist[b,y] - dist[b, top2-excluding-y-at-top1]), y=argmax(label[b])
//
// R9: R8 proved the systemic failure mode of R1..R8: ~1 outstanding load per
// wave (VGPR 24!) -> pure serialized memory latency, 46-60 us regardless of
// structure. Fix: FORCE 16-deep memory pipelining with 16 NAMED float4 loads
// per chunk (no consumer between them -> compiler must issue back-to-back),
// JB=2 rows/wave + grid 512 (2 waves/SIMD) to cover chunk-boundary bubbles.
// Named scalars, NOT arrays: register-array prefetch twice produced 45-118 MB
// anomalous HBM writes (R2/R4). W rows on the scalar stream (readfirstlane,
// lgkm) -- zero ds_reads in the kernel, so lgkm drains touch only SMEM
// (R7's lgkm-sharing poison absent). No LDS, no barriers in the hot loop.
#define NB 4096
#define NR 64
#define JB 2            // b-rows per wave
#define WVS 4           // waves per block
#define BBB (JB * WVS)  // 8 b-rows per block; grid = 512

__global__ __launch_bounds__(256) void transpose_re_kernel(
    const float* __restrict__ re, float4* __restrict__ reT)
{
    // reT[d4*64 + r] = float4 of re[r][4*d4 .. 4*d4+3]
    int t  = blockIdx.x * 256 + threadIdx.x;    // 8192 threads: grid 32
    int r  = t >> 7;                            // relation row
    int d4 = t & 127;                           // f4 column
    reT[d4 * 64 + r] = ((const float4*)re)[r * 128 + d4];
}

__global__ __launch_bounds__(256) void fused_loss_kernel(
    const float* __restrict__ w,
    const float4* __restrict__ reT,
    const float* __restrict__ label,
    float* __restrict__ out,
    float* __restrict__ ws)
{
    __shared__ float terms[WVS];

    const int tid = threadIdx.x;
    const int wv  = tid >> 6;       // wave id
    const int r   = tid & 63;       // lane = relation 0..63
    const int b0  = blockIdx.x * BBB;

    // W row base pointers, readfirstlane-forced scalar
    const float4* wr0;
    const float4* wr1;
    {
        int bu0 = __builtin_amdgcn_readfirstlane(b0 + wv * JB + 0);
        int bu1 = __builtin_amdgcn_readfirstlane(b0 + wv * JB + 1);
        wr0 = (const float4*)(w + (size_t)bu0 * 512);
        wr1 = (const float4*)(w + (size_t)bu1 * 512);
    }

    float4 acc0 = {0.f, 0.f, 0.f, 0.f};
    float4 acc1 = {0.f, 0.f, 0.f, 0.f};

    // hot loop: 8 chunks of 16 d4. Each chunk: 16 NAMED reT loads issued
    // back-to-back (16-deep vmcnt pipeline), then 2x16x8 VALU consuming them.
    for (int c = 0; c < 8; c++) {
        const float4* rp = reT + (size_t)c * 16 * 64 + r;

        float4 v0  = rp[0 * 64],  v1  = rp[1 * 64],  v2  = rp[2 * 64],  v3  = rp[3 * 64];
        float4 v4  = rp[4 * 64],  v5  = rp[5 * 64],  v6  = rp[6 * 64],  v7  = rp[7 * 64];
        float4 v8  = rp[8 * 64],  v9  = rp[9 * 64],  v10 = rp[10 * 64], v11 = rp[11 * 64];
        float4 v12 = rp[12 * 64], v13 = rp[13 * 64], v14 = rp[14 * 64], v15 = rp[15 * 64];

#define STEP(i, vv)                                                          \
        {                                                                    \
            float4 a0 = wr0[c * 16 + (i)];       /* scalar (lgkm) stream */  \
            float4 a1 = wr1[c * 16 + (i)];                                   \
            float dx;                                                        \
            dx = a0.x - vv.x; acc0.x = fmaf(dx, dx, acc0.x);                 \
            dx = a0.y - vv.y; acc0.y = fmaf(dx, dx, acc0.y);                 \
            dx = a0.z - vv.z; acc0.z = fmaf(dx, dx, acc0.z);                 \
            dx = a0.w - vv.w; acc0.w = fmaf(dx, dx, acc0.w);                 \
            dx = a1.x - vv.x; acc1.x = fmaf(dx, dx, acc1.x);                 \
            dx = a1.y - vv.y; acc1.y = fmaf(dx, dx, acc1.y);                 \
            dx = a1.z - vv.z; acc1.z = fmaf(dx, dx, acc1.z);                 \
            dx = a1.w - vv.w; acc1.w = fmaf(dx, dx, acc1.w);                 \
        }

        STEP(0,  v0)  STEP(1,  v1)  STEP(2,  v2)  STEP(3,  v3)
        STEP(4,  v4)  STEP(5,  v5)  STEP(6,  v6)  STEP(7,  v7)
        STEP(8,  v8)  STEP(9,  v9)  STEP(10, v10) STEP(11, v11)
        STEP(12, v12) STEP(13, v13) STEP(14, v14) STEP(15, v15)
#undef STEP
    }

    // ---- epilogue per j: top-2/argmax + label argmax + loss term ----
    float lsum = 0.0f;
    #pragma unroll
    for (int j = 0; j < JB; j++) {
        int b = b0 + wv * JB + j;
        float4 accj = (j == 0) ? acc0 : acc1;
        float d = sqrtf((accj.x + accj.y) + (accj.z + accj.w));

        float m1 = d; int i1 = r; float m2 = -3.0e38f;
        #pragma unroll
        for (int mask = 1; mask <= 32; mask <<= 1) {
            float om1 = __shfl_xor(m1, mask, 64);
            int   oi1 = __shfl_xor(i1, mask, 64);
            float om2 = __shfl_xor(m2, mask, 64);
            bool ob1 = (om1 > m1) || (om1 == m1 && oi1 < i1);
            float w1 = ob1 ? om1 : m1;  int wi1 = ob1 ? oi1 : i1;
            float l1 = ob1 ? m1 : om1;          // loser's top-1 (value only)
            float c2 = ob1 ? om2 : m2;          // winner's top-2 (value only)
            m1 = w1; i1 = wi1;
            m2 = (c2 > l1) ? c2 : l1;
        }

        float lv = label[(size_t)b * 64 + r]; int ly = r;
        #pragma unroll
        for (int mask = 1; mask <= 32; mask <<= 1) {
            float ov = __shfl_xor(lv, mask, 64);
            int   oy = __shfl_xor(ly, mask, 64);
            if (ov > lv || (ov == lv && oy < ly)) { lv = ov; ly = oy; }
        }
        int y = ly;

        float plus  = __shfl(d, y, 64);       // dist[b][y]
        float minus = (i1 == y) ? m2 : m1;    // top-2 value if top-1 == y
        lsum += 1.0f + plus - minus;

        out[(size_t)b * 64 + r] = (i1 == r) ? 1.0f : 0.0f;   // pred one-hot
    }

    if (r == 0) terms[wv] = lsum;

    // ---- fused loss reduction: block partial -> device atomic -> last block
    __syncthreads();
    if (tid == 0) {
        float t = ((terms[0] + terms[1]) + (terms[2] + terms[3])) * (1.0f / NB);
        atomicAdd(ws, t);                     // ws[0] = loss accumulator (zeroed)
        __threadfence();                      // order add before counter inc
        unsigned old = atomicAdd((unsigned*)(ws + 1), 1u);   // ws[1] = counter
        if (old == (unsigned)(gridDim.x - 1)) {
            float total = atomicAdd(ws, 0.0f);   // all 512 adds visible
            out[(size_t)NB * NR] = total;
        }
    }
}

extern "C" void kernel_launch(void* const* d_in, const int* in_sizes, int n_in,
                              void* d_out, int out_size, void* d_ws, size_t ws_size,
                              hipStream_t stream) {
    const float* w   = (const float*)d_in[0];   // [4096,512]
    const float* re  = (const float*)d_in[1];   // [64,512]
    const float* lab = (const float*)d_in[2];   // [4096,64]
    float* out = (float*)d_out;                 // pred [4096,64] ++ loss [1]
    float* ws  = (float*)d_ws;                  // [0]=loss acc, [1]=done counter
    float4* reT = (float4*)((char*)d_ws + 1024);// [128][64] f4 = 128 KB scratch

    hipMemsetAsync(ws, 0, 8, stream);           // zero acc + counter (graph-safe)
    transpose_re_kernel<<<32, 256, 0, stream>>>(re, reT);
    fused_loss_kernel<<<NB / BBB, 256, 0, stream>>>(w, reT, lab, out, ws);
}

// Round 11
// 92.086 us; speedup vs baseline: 1.2808x; 1.0449x over previous
//
#include <hip/hip_runtime.h>
#include <math.h>

// LossLayer: dist[b,r] = ||W[b]-R[r]||2 ; pred = one_hot(argmax_r dist) ;
// loss = mean(1 + dist[b,y] - dist[b, top2-excluding-y-at-top1]), y=argmax(label[b])
//
// R11: revert to R9's PROVEN skeleton (R10's deep unroll core-dumped).
// R9's residual stall: W read via s_load -- SMEM is OUT-OF-ORDER, so every
// scalar-result use forces lgkmcnt(0) (~128 serialized SMEM round-trips/wave).
// Fix: W tile (8 rows, 16 KB) staged ONCE via global_load_lds + ONE barrier;
// hot loop reads W with wave-uniform ds_read_b128 (broadcast, conflict-free,
// DS is IN-ORDER -> fine-grained lgkmcnt(N) waits). Hot loop has zero s_loads,
// zero barriers. reT vector stream: R9's named 16-load batches (the thing
// that broke the 46-60us wall). JB=2, grid 512 (2 blocks/CU, 8 waves/CU).
#define NB 4096
#define NR 64
#define JB 2            // b-rows per wave
#define WVS 4           // waves per block
#define BBB (JB * WVS)  // 8 b-rows per block; grid = 512

#define AS1 __attribute__((address_space(1)))
#define AS3 __attribute__((address_space(3)))

__device__ __forceinline__ void async_copy16(void* lds, const void* g) {
    __builtin_amdgcn_global_load_lds((const AS1 void*)g, (AS3 void*)lds, 16, 0, 0);
}

__global__ __launch_bounds__(256) void transpose_re_kernel(
    const float* __restrict__ re, float4* __restrict__ reT)
{
    // reT[d4*64 + r] = float4 of re[r][4*d4 .. 4*d4+3]
    int t  = blockIdx.x * 256 + threadIdx.x;    // 8192 threads: grid 32
    int r  = t >> 7;                            // relation row
    int d4 = t & 127;                           // f4 column
    reT[d4 * 64 + r] = ((const float4*)re)[r * 128 + d4];
}

__global__ __launch_bounds__(256) void fused_loss_kernel(
    const float* __restrict__ w,
    const float4* __restrict__ reT,
    const float* __restrict__ label,
    float* __restrict__ out,
    float* __restrict__ ws)
{
    __shared__ float4 wl[BBB * 128];   // 8 W rows, 16 KB (uniform reads only)
    __shared__ float terms[WVS];

    const int tid = threadIdx.x;
    const int wv  = tid >> 6;       // wave id
    const int r   = tid & 63;       // lane = relation 0..63
    const int b0  = blockIdx.x * BBB;

    // ---- stage W tile once: wave wv stages its own 2 rows (contiguous) ----
    {
        const float4* w4a = (const float4*)(w + (size_t)(b0 + wv * JB + 0) * 512);
        const float4* w4b = (const float4*)(w + (size_t)(b0 + wv * JB + 1) * 512);
        async_copy16(&wl[(wv * JB + 0) * 128],      w4a + r);
        async_copy16(&wl[(wv * JB + 0) * 128 + 64], w4a + 64 + r);
        async_copy16(&wl[(wv * JB + 1) * 128],      w4b + r);
        async_copy16(&wl[(wv * JB + 1) * 128 + 64], w4b + 64 + r);
    }
    __syncthreads();   // ONE drain at startup; hot loop is barrier-free

    const float4* l0 = &wl[(wv * JB + 0) * 128];   // wave-uniform LDS rows
    const float4* l1 = &wl[(wv * JB + 1) * 128];

    float4 acc0 = {0.f, 0.f, 0.f, 0.f};
    float4 acc1 = {0.f, 0.f, 0.f, 0.f};

    // hot loop: 8 chunks of 16 d4. Per chunk: 16 NAMED reT loads issued
    // back-to-back (16-deep vmcnt pipeline, R9-proven), consumed with
    // wave-uniform ds_read_b128 W broadcasts (in-order lgkm, fine waits).
    for (int c = 0; c < 8; c++) {
        const float4* rp = reT + (size_t)c * 1024 + r;

        float4 v0  = rp[0],    v1  = rp[64],   v2  = rp[128],  v3  = rp[192];
        float4 v4  = rp[256],  v5  = rp[320],  v6  = rp[384],  v7  = rp[448];
        float4 v8  = rp[512],  v9  = rp[576],  v10 = rp[640],  v11 = rp[704];
        float4 v12 = rp[768],  v13 = rp[832],  v14 = rp[896],  v15 = rp[960];

#define STEP(i, vv)                                                          \
        {                                                                    \
            float4 q0 = l0[c * 16 + (i)];      /* uniform ds_read_b128 */    \
            float4 q1 = l1[c * 16 + (i)];                                    \
            float dx;                                                        \
            dx = q0.x - vv.x; acc0.x = fmaf(dx, dx, acc0.x);                 \
            dx = q0.y - vv.y; acc0.y = fmaf(dx, dx, acc0.y);                 \
            dx = q0.z - vv.z; acc0.z = fmaf(dx, dx, acc0.z);                 \
            dx = q0.w - vv.w; acc0.w = fmaf(dx, dx, acc0.w);                 \
            dx = q1.x - vv.x; acc1.x = fmaf(dx, dx, acc1.x);                 \
            dx = q1.y - vv.y; acc1.y = fmaf(dx, dx, acc1.y);                 \
            dx = q1.z - vv.z; acc1.z = fmaf(dx, dx, acc1.z);                 \
            dx = q1.w - vv.w; acc1.w = fmaf(dx, dx, acc1.w);                 \
        }

        STEP(0,  v0)  STEP(1,  v1)  STEP(2,  v2)  STEP(3,  v3)
        STEP(4,  v4)  STEP(5,  v5)  STEP(6,  v6)  STEP(7,  v7)
        STEP(8,  v8)  STEP(9,  v9)  STEP(10, v10) STEP(11, v11)
        STEP(12, v12) STEP(13, v13) STEP(14, v14) STEP(15, v15)
#undef STEP
    }

    // ---- epilogue per j: top-2/argmax + label argmax + loss term ----
    float lsum = 0.0f;
    #pragma unroll
    for (int j = 0; j < JB; j++) {
        int b = b0 + wv * JB + j;
        float4 accj = (j == 0) ? acc0 : acc1;
        float d = sqrtf((accj.x + accj.y) + (accj.z + accj.w));

        float m1 = d; int i1 = r; float m2 = -3.0e38f;
        #pragma unroll
        for (int mask = 1; mask <= 32; mask <<= 1) {
            float om1 = __shfl_xor(m1, mask, 64);
            int   oi1 = __shfl_xor(i1, mask, 64);
            float om2 = __shfl_xor(m2, mask, 64);
            bool ob1 = (om1 > m1) || (om1 == m1 && oi1 < i1);
            float w1 = ob1 ? om1 : m1;  int wi1 = ob1 ? oi1 : i1;
            float l1_ = ob1 ? m1 : om1;         // loser's top-1 (value only)
            float c2 = ob1 ? om2 : m2;          // winner's top-2 (value only)
            m1 = w1; i1 = wi1;
            m2 = (c2 > l1_) ? c2 : l1_;
        }

        float lv = label[(size_t)b * 64 + r]; int ly = r;
        #pragma unroll
        for (int mask = 1; mask <= 32; mask <<= 1) {
            float ov = __shfl_xor(lv, mask, 64);
            int   oy = __shfl_xor(ly, mask, 64);
            if (ov > lv || (ov == lv && oy < ly)) { lv = ov; ly = oy; }
        }
        int y = ly;

        float plus  = __shfl(d, y, 64);       // dist[b][y]
        float minus = (i1 == y) ? m2 : m1;    // top-2 value if top-1 == y
        lsum += 1.0f + plus - minus;

        out[(size_t)b * 64 + r] = (i1 == r) ? 1.0f : 0.0f;   // pred one-hot
    }

    if (r == 0) terms[wv] = lsum;

    // ---- fused loss reduction: block partial -> device atomic -> last block
    __syncthreads();
    if (tid == 0) {
        float t = ((terms[0] + terms[1]) + (terms[2] + terms[3])) * (1.0f / NB);
        atomicAdd(ws, t);                     // ws[0] = loss accumulator (zeroed)
        __threadfence();                      // order add before counter inc
        unsigned old = atomicAdd((unsigned*)(ws + 1), 1u);   // ws[1] = counter
        if (old == (unsigned)(gridDim.x - 1)) {
            float total = atomicAdd(ws, 0.0f);   // all 512 adds visible
            out[(size_t)NB * NR] = total;
        }
    }
}

extern "C" void kernel_launch(void* const* d_in, const int* in_sizes, int n_in,
                              void* d_out, int out_size, void* d_ws, size_t ws_size,
                              hipStream_t stream) {
    const float* w   = (const float*)d_in[0];   // [4096,512]
    const float* re  = (const float*)d_in[1];   // [64,512]
    const float* lab = (const float*)d_in[2];   // [4096,64]
    float* out = (float*)d_out;                 // pred [4096,64] ++ loss [1]
    float* ws  = (float*)d_ws;                  // [0]=loss acc, [1]=done counter
    float4* reT = (float4*)((char*)d_ws + 1024);// [128][64] f4 = 128 KB scratch

    hipMemsetAsync(ws, 0, 8, stream);           // zero acc + counter (graph-safe)
    transpose_re_kernel<<<32, 256, 0, stream>>>(re, reT);
    fused_loss_kernel<<<NB / BBB, 256, 0, stream>>>(w, reT, lab, out, ws);
}

// Round 12
// 84.338 us; speedup vs baseline: 1.3985x; 1.0919x over previous
//
#include <hip/hip_runtime.h>
#include <math.h>

// LossLayer: dist[b,r] = ||W[b]-R[r]||2 ; pred = one_hot(argmax_r dist) ;
// loss = mean(1 + dist[b,y] - dist[b, top2-excluding-y-at-top1]), y=argmax(label[b])
//
// R12: R11's fused kernel still ~35-40us (hidden under the 41us harness fill
// floor). Its waste: vector pipe carried 1 MB/CU of reT (8 waves x 128 KB,
// cross-XCD L2 misses) and LDS carried 2048 BROADCAST ds_reads (16 B useful
// of 1 KB peak each). Fix: put ALL of reT (128 KB <= 160 KB) in LDS once
// (coalesced global_load_lds, ONE barrier), read it LANE-VARYING at full
// 1 KB/instr LDS BW (consecutive lanes -> consecutive 16 B, conflict-free);
// W becomes the broadcast operand via UNIFORM-address global vector loads
// (vmcnt stream, independent of lgkm; 16 named loads per 8-d4 group, batch
// issued, latency covered by 2 waves/SIMD). grid 256, block 512, JB=2.
#define NB 4096
#define NR 64
#define JB 2            // b-rows per wave
#define WVS 8           // waves per block (512 threads)
#define BBB (JB * WVS)  // 16 b-rows per block; grid = 256

#define AS1 __attribute__((address_space(1)))
#define AS3 __attribute__((address_space(3)))

__device__ __forceinline__ void async_copy16(void* lds, const void* g) {
    __builtin_amdgcn_global_load_lds((const AS1 void*)g, (AS3 void*)lds, 16, 0, 0);
}

__global__ __launch_bounds__(256) void transpose_re_kernel(
    const float* __restrict__ re, float4* __restrict__ reT)
{
    // reT[d4*64 + r] = float4 of re[r][4*d4 .. 4*d4+3]
    int t  = blockIdx.x * 256 + threadIdx.x;    // 8192 threads: grid 32
    int r  = t >> 7;                            // relation row
    int d4 = t & 127;                           // f4 column
    reT[d4 * 64 + r] = ((const float4*)re)[r * 128 + d4];
}

__global__ __launch_bounds__(512) void fused_loss_kernel(
    const float* __restrict__ w,
    const float4* __restrict__ reT,
    const float* __restrict__ label,
    float* __restrict__ out,
    float* __restrict__ ws)
{
    __shared__ float4 rl[128 * 64];    // ALL of reT: 128 KB (fits 160 KB/CU)
    __shared__ float terms[WVS];

    const int tid = threadIdx.x;
    const int wv  = tid >> 6;       // wave id 0..7
    const int r   = tid & 63;       // lane = relation 0..63
    const int b0  = blockIdx.x * BBB;

    // ---- stage ALL of reT into LDS once: 128 instrs, coalesced both sides
    #pragma unroll
    for (int j = 0; j < 16; j++) {
        int s = (wv * 16 + j) * 64;            // wave-uniform base slot
        async_copy16(&rl[s], reT + s + r);
    }

    // uniform W row pointers (readfirstlane -> scalar addr; data broadcast)
    const float4* wr0;
    const float4* wr1;
    {
        int bu0 = __builtin_amdgcn_readfirstlane(b0 + wv * JB + 0);
        int bu1 = __builtin_amdgcn_readfirstlane(b0 + wv * JB + 1);
        wr0 = (const float4*)(w + (size_t)bu0 * 512);
        wr1 = (const float4*)(w + (size_t)bu1 * 512);
    }

    float4 acc0 = {0.f, 0.f, 0.f, 0.f};
    float4 acc1 = {0.f, 0.f, 0.f, 0.f};

    __syncthreads();   // ONE drain: all of re resident; loop is barrier-free

    // hot loop: 16 groups of 8 d4. Per group: 16 named uniform W loads
    // (vmcnt, batch-issued broadcast) + 8 named lane-varying ds_read_b128
    // (full LDS BW, conflict-free) + 128 VALU.
    for (int g = 0; g < 16; g++) {
        const int gb = g * 8;

        float4 qa0 = wr0[gb+0], qa1 = wr0[gb+1], qa2 = wr0[gb+2], qa3 = wr0[gb+3];
        float4 qa4 = wr0[gb+4], qa5 = wr0[gb+5], qa6 = wr0[gb+6], qa7 = wr0[gb+7];
        float4 qb0 = wr1[gb+0], qb1 = wr1[gb+1], qb2 = wr1[gb+2], qb3 = wr1[gb+3];
        float4 qb4 = wr1[gb+4], qb5 = wr1[gb+5], qb6 = wr1[gb+6], qb7 = wr1[gb+7];

        const float4* rp = &rl[gb * 64 + r];
        float4 v0 = rp[0],   v1 = rp[64],  v2 = rp[128], v3 = rp[192];
        float4 v4 = rp[256], v5 = rp[320], v6 = rp[384], v7 = rp[448];

#define STEP(qa, qb, vv)                                                     \
        {                                                                    \
            float dx;                                                        \
            dx = qa.x - vv.x; acc0.x = fmaf(dx, dx, acc0.x);                 \
            dx = qa.y - vv.y; acc0.y = fmaf(dx, dx, acc0.y);                 \
            dx = qa.z - vv.z; acc0.z = fmaf(dx, dx, acc0.z);                 \
            dx = qa.w - vv.w; acc0.w = fmaf(dx, dx, acc0.w);                 \
            dx = qb.x - vv.x; acc1.x = fmaf(dx, dx, acc1.x);                 \
            dx = qb.y - vv.y; acc1.y = fmaf(dx, dx, acc1.y);                 \
            dx = qb.z - vv.z; acc1.z = fmaf(dx, dx, acc1.z);                 \
            dx = qb.w - vv.w; acc1.w = fmaf(dx, dx, acc1.w);                 \
        }
        STEP(qa0, qb0, v0) STEP(qa1, qb1, v1) STEP(qa2, qb2, v2) STEP(qa3, qb3, v3)
        STEP(qa4, qb4, v4) STEP(qa5, qb5, v5) STEP(qa6, qb6, v6) STEP(qa7, qb7, v7)
#undef STEP
    }

    // ---- epilogue per j: top-2/argmax + label argmax + loss term ----
    float lsum = 0.0f;
    #pragma unroll
    for (int j = 0; j < JB; j++) {
        int b = b0 + wv * JB + j;
        float4 accj = (j == 0) ? acc0 : acc1;
        float d = sqrtf((accj.x + accj.y) + (accj.z + accj.w));

        float m1 = d; int i1 = r; float m2 = -3.0e38f;
        #pragma unroll
        for (int mask = 1; mask <= 32; mask <<= 1) {
            float om1 = __shfl_xor(m1, mask, 64);
            int   oi1 = __shfl_xor(i1, mask, 64);
            float om2 = __shfl_xor(m2, mask, 64);
            bool ob1 = (om1 > m1) || (om1 == m1 && oi1 < i1);
            float w1 = ob1 ? om1 : m1;  int wi1 = ob1 ? oi1 : i1;
            float l1_ = ob1 ? m1 : om1;         // loser's top-1 (value only)
            float c2 = ob1 ? om2 : m2;          // winner's top-2 (value only)
            m1 = w1; i1 = wi1;
            m2 = (c2 > l1_) ? c2 : l1_;
        }

        float lv = label[(size_t)b * 64 + r]; int ly = r;
        #pragma unroll
        for (int mask = 1; mask <= 32; mask <<= 1) {
            float ov = __shfl_xor(lv, mask, 64);
            int   oy = __shfl_xor(ly, mask, 64);
            if (ov > lv || (ov == lv && oy < ly)) { lv = ov; ly = oy; }
        }
        int y = ly;

        float plus  = __shfl(d, y, 64);       // dist[b][y]
        float minus = (i1 == y) ? m2 : m1;    // top-2 value if top-1 == y
        lsum += 1.0f + plus - minus;

        out[(size_t)b * 64 + r] = (i1 == r) ? 1.0f : 0.0f;   // pred one-hot
    }

    if (r == 0) terms[wv] = lsum;

    // ---- fused loss reduction: block partial -> device atomic -> last block
    __syncthreads();
    if (tid == 0) {
        float t = (((terms[0] + terms[1]) + (terms[2] + terms[3]))
                 + ((terms[4] + terms[5]) + (terms[6] + terms[7]))) * (1.0f / NB);
        atomicAdd(ws, t);                     // ws[0] = loss accumulator (zeroed)
        __threadfence();                      // order add before counter inc
        unsigned old = atomicAdd((unsigned*)(ws + 1), 1u);   // ws[1] = counter
        if (old == (unsigned)(gridDim.x - 1)) {
            float total = atomicAdd(ws, 0.0f);   // all 256 adds visible
            out[(size_t)NB * NR] = total;
        }
    }
}

extern "C" void kernel_launch(void* const* d_in, const int* in_sizes, int n_in,
                              void* d_out, int out_size, void* d_ws, size_t ws_size,
                              hipStream_t stream) {
    const float* w   = (const float*)d_in[0];   // [4096,512]
    const float* re  = (const float*)d_in[1];   // [64,512]
    const float* lab = (const float*)d_in[2];   // [4096,64]
    float* out = (float*)d_out;                 // pred [4096,64] ++ loss [1]
    float* ws  = (float*)d_ws;                  // [0]=loss acc, [1]=done counter
    float4* reT = (float4*)((char*)d_ws + 1024);// [128][64] f4 = 128 KB scratch

    hipMemsetAsync(ws, 0, 8, stream);           // zero acc + counter (graph-safe)
    transpose_re_kernel<<<32, 256, 0, stream>>>(re, reT);
    fused_loss_kernel<<<NB / BBB, 512, 0, stream>>>(w, reT, lab, out, ws);
}

// Round 13
// 81.683 us; speedup vs baseline: 1.4440x; 1.0325x over previous
//
#include <hip/hip_runtime.h>
#include <math.h>

// LossLayer: dist[b,r] = ||W[b]-R[r]||2 ; pred = one_hot(argmax_r dist) ;
// loss = mean(1 + dist[b,y] - dist[b, top2-excluding-y-at-top1]), y=argmax(label[b])
//
// R13 (on R12's best-yet structure): (1) transpose kernel MERGED into the
// fused kernel -- each block stages re row-major (coalesced named loads,
// consumed immediately by ds_write: no spillable live range) into LDS
// TRANSPOSED with stride-65 f4 padding: slot = d4*65 + r. Writes rotate
// banks by 4/lane (<=8-way, one-time ~500 cyc); hot-loop reads are
// lane-consecutive 16 B = conflict-free, zero extra VALU (65*16=1040 B
// immediate offsets). Kills one kernel launch + the reT L2 round-trip.
// (2) inner math on ext_vector_type(4) floats -> backend may select
// v_pk_fma_f32 (packed dual-FMA): up to 2x fewer VALU instrs, identical
// 4-chain fp32 numerics. (3) label loads hoisted above the barrier;
// unroll-4 group loop lets the scheduler hoist W(g+1) in the barrier-free
// body. Grid 256 x block 512 (1 block/CU), JB=2, W uniform vmcnt loads.
#define NB 4096
#define NR 64
#define JB 2            // b-rows per wave
#define WVS 8           // waves per block (512 threads)
#define BBB (JB * WVS)  // 16 b-rows per block; grid = 256

typedef float f4v __attribute__((ext_vector_type(4)));

__global__ __launch_bounds__(512) void fused_loss_kernel(
    const float* __restrict__ w,
    const float* __restrict__ re,
    const float* __restrict__ label,
    float* __restrict__ out,
    float* __restrict__ ws)
{
    __shared__ f4v rl[128 * 65];    // transposed+padded re: slot=d4*65+r, 130 KB
    __shared__ float terms[WVS];

    const int tid = threadIdx.x;
    const int wv  = tid >> 6;       // wave id 0..7
    const int r   = tid & 63;       // lane = relation 0..63
    const int b0  = blockIdx.x * BBB;

    // ---- stage re row-major -> LDS transposed (one-time) ----
    // thread t, iter i: global f4 idx = i*512+t; row=idx>>7, d4=idx&127.
    // Loads coalesced (1 KB/wave); ds_write banks rotate 4/lane (pad 65).
    const f4v* re4g = (const f4v*)re;
    #pragma unroll
    for (int i = 0; i < 16; i++) {
        int idx = i * 512 + tid;
        f4v v = re4g[idx];                       // named temp, consumed at once
        rl[(idx & 127) * 65 + (idx >> 7)] = v;
    }

    // ---- hoisted label loads (latency hidden under staging) ----
    const int b_0 = b0 + wv * JB;
    const int b_1 = b_0 + 1;
    float lv_0 = label[(size_t)b_0 * 64 + r];
    float lv_1 = label[(size_t)b_1 * 64 + r];

    // uniform W row pointers (readfirstlane -> scalar addr; broadcast data)
    const f4v* wr0;
    const f4v* wr1;
    {
        int bu0 = __builtin_amdgcn_readfirstlane(b_0);
        int bu1 = __builtin_amdgcn_readfirstlane(b_1);
        wr0 = (const f4v*)(w + (size_t)bu0 * 512);
        wr1 = (const f4v*)(w + (size_t)bu1 * 512);
    }

    f4v acc0 = {0.f, 0.f, 0.f, 0.f};
    f4v acc1 = {0.f, 0.f, 0.f, 0.f};

    __syncthreads();   // ONE drain: re resident+transposed; loop barrier-free

    // hot loop: 16 groups of 8 d4. Per group: 16 uniform W vector loads
    // (vmcnt broadcast) + 8 lane-consecutive ds_read_b128 (conflict-free)
    // + packed-f32 FMA. unroll-4 gives the scheduler a hoisting window.
    #pragma unroll 4
    for (int g = 0; g < 16; g++) {
        const int gb = g * 8;

        f4v qa0 = wr0[gb+0], qa1 = wr0[gb+1], qa2 = wr0[gb+2], qa3 = wr0[gb+3];
        f4v qa4 = wr0[gb+4], qa5 = wr0[gb+5], qa6 = wr0[gb+6], qa7 = wr0[gb+7];
        f4v qb0 = wr1[gb+0], qb1 = wr1[gb+1], qb2 = wr1[gb+2], qb3 = wr1[gb+3];
        f4v qb4 = wr1[gb+4], qb5 = wr1[gb+5], qb6 = wr1[gb+6], qb7 = wr1[gb+7];

        const f4v* rp = &rl[gb * 65 + r];        // slot=(gb+k)*65+r
        f4v v0 = rp[0*65], v1 = rp[1*65], v2 = rp[2*65], v3 = rp[3*65];
        f4v v4 = rp[4*65], v5 = rp[5*65], v6 = rp[6*65], v7 = rp[7*65];

#define STEP(qa, qb, vv)                                                     \
        {                                                                    \
            f4v dxa = qa - vv;  acc0 = dxa * dxa + acc0;                     \
            f4v dxb = qb - vv;  acc1 = dxb * dxb + acc1;                     \
        }
        STEP(qa0, qb0, v0) STEP(qa1, qb1, v1) STEP(qa2, qb2, v2) STEP(qa3, qb3, v3)
        STEP(qa4, qb4, v4) STEP(qa5, qb5, v5) STEP(qa6, qb6, v6) STEP(qa7, qb7, v7)
#undef STEP
    }

    // ---- epilogue per j: top-2/argmax + label argmax + loss term ----
    float lsum = 0.0f;
    #pragma unroll
    for (int j = 0; j < JB; j++) {
        int b = (j == 0) ? b_0 : b_1;
        f4v accj = (j == 0) ? acc0 : acc1;
        float d = sqrtf((accj.x + accj.y) + (accj.z + accj.w));

        float m1 = d; int i1 = r; float m2 = -3.0e38f;
        #pragma unroll
        for (int mask = 1; mask <= 32; mask <<= 1) {
            float om1 = __shfl_xor(m1, mask, 64);
            int   oi1 = __shfl_xor(i1, mask, 64);
            float om2 = __shfl_xor(m2, mask, 64);
            bool ob1 = (om1 > m1) || (om1 == m1 && oi1 < i1);
            float w1 = ob1 ? om1 : m1;  int wi1 = ob1 ? oi1 : i1;
            float l1_ = ob1 ? m1 : om1;         // loser's top-1 (value only)
            float c2 = ob1 ? om2 : m2;          // winner's top-2 (value only)
            m1 = w1; i1 = wi1;
            m2 = (c2 > l1_) ? c2 : l1_;
        }

        float lv = (j == 0) ? lv_0 : lv_1; int ly = r;
        #pragma unroll
        for (int mask = 1; mask <= 32; mask <<= 1) {
            float ov = __shfl_xor(lv, mask, 64);
            int   oy = __shfl_xor(ly, mask, 64);
            if (ov > lv || (ov == lv && oy < ly)) { lv = ov; ly = oy; }
        }
        int y = ly;

        float plus  = __shfl(d, y, 64);       // dist[b][y]
        float minus = (i1 == y) ? m2 : m1;    // top-2 value if top-1 == y
        lsum += 1.0f + plus - minus;

        out[(size_t)b * 64 + r] = (i1 == r) ? 1.0f : 0.0f;   // pred one-hot
    }

    if (r == 0) terms[wv] = lsum;

    // ---- fused loss reduction: block partial -> device atomic -> last block
    __syncthreads();
    if (tid == 0) {
        float t = (((terms[0] + terms[1]) + (terms[2] + terms[3]))
                 + ((terms[4] + terms[5]) + (terms[6] + terms[7]))) * (1.0f / NB);
        atomicAdd(ws, t);                     // ws[0] = loss accumulator (zeroed)
        __threadfence();                      // order add before counter inc
        unsigned old = atomicAdd((unsigned*)(ws + 1), 1u);   // ws[1] = counter
        if (old == (unsigned)(gridDim.x - 1)) {
            float total = atomicAdd(ws, 0.0f);   // all 256 adds visible
            out[(size_t)NB * NR] = total;
        }
    }
}

extern "C" void kernel_launch(void* const* d_in, const int* in_sizes, int n_in,
                              void* d_out, int out_size, void* d_ws, size_t ws_size,
                              hipStream_t stream) {
    const float* w   = (const float*)d_in[0];   // [4096,512]
    const float* re  = (const float*)d_in[1];   // [64,512]
    const float* lab = (const float*)d_in[2];   // [4096,64]
    float* out = (float*)d_out;                 // pred [4096,64] ++ loss [1]
    float* ws  = (float*)d_ws;                  // [0]=loss acc, [1]=done counter

    hipMemsetAsync(ws, 0, 8, stream);           // zero acc + counter (graph-safe)
    fused_loss_kernel<<<NB / BBB, 512, 0, stream>>>(w, re, lab, out, ws);
}